// Round 9
// baseline (324.428 us; speedup 1.0000x reference)
//
#include <hip/hip_runtime.h>

typedef unsigned short u16;
typedef unsigned int u32;
typedef short bf16x8 __attribute__((ext_vector_type(8)));
typedef float f32x4 __attribute__((ext_vector_type(4)));

#define MFMA16(a, b, c) __builtin_amdgcn_mfma_f32_16x16x32_bf16((a), (b), (c), 0, 0, 0)

__device__ __forceinline__ u16 f2bf(float f) {
  u32 u = __builtin_bit_cast(u32, f);
  u += 0x7FFFu + ((u >> 16) & 1u);
  return (u16)(u >> 16);
}
// packed f32x2 -> bf16x2; HW builtin when available, software RNE otherwise
__device__ __forceinline__ u32 pk2bf(float a, float b) {
#if __has_builtin(__builtin_amdgcn_cvt_pk_bf16_f32)
  auto v = __builtin_amdgcn_cvt_pk_bf16_f32(a, b);
  return __builtin_bit_cast(u32, v);
#else
  return (u32)f2bf(a) | ((u32)f2bf(b) << 16);
#endif
}

// ws byte offsets (prep layouts identical to R8 -- verified)
#define WS_MGF   0         // bf16 [8 jt][64 lane][8 j]      B-frags of M^T   (8192 B)
#define WS_WT1F  8192      // bf16 [8 ot][2 h][4 ks][64][8]  B-frags of Wp1   (65536 B)
#define WS_WT2F  73728     // bf16 [8 mt][4 h][4 ks][64][8]  A-frags of Wp2^T (131072 B)
#define WS_B1    204800    // f32 [128]  bias1 + T0-fold
#define WS_B2    205312    // f32 [128]  bias2 + T0-fold

__global__ void prep_kernel(const float* __restrict__ adj,
                            const float* __restrict__ adj_bias,
                            const float* __restrict__ w1,
                            const float* __restrict__ b1,
                            const float* __restrict__ w2,
                            const float* __restrict__ b2,
                            char* __restrict__ ws) {
  const int tid = threadIdx.x;
  if (blockIdx.x == 0) {
    __shared__ float sa[1024], Ls[1024], L2s[1024], L3s[1024], sdre[32];
    float bias = adj_bias[0];
    for (int i = tid; i < 1024; i += 256) sa[i] = fmaxf(adj[i] + bias, 0.0f);
    __syncthreads();
    if (tid < 32) {
      float s = 0.0f;
      for (int c = 0; c < 32; ++c) s += sa[tid * 32 + c];
      sdre[tid] = 1.0f / sqrtf(s + 1e-5f);
    }
    __syncthreads();
    for (int i = tid; i < 1024; i += 256) {
      int n = i >> 5, c = i & 31;
      Ls[i] = (n == c ? 1.0f : 0.0f) - sdre[n] * sa[i] * sdre[c];
    }
    __syncthreads();
    for (int i = tid; i < 1024; i += 256) {
      int r = i >> 5, c = i & 31;
      float s = 0.0f;
      for (int m = 0; m < 32; ++m) s += Ls[r * 32 + m] * Ls[m * 32 + c];
      L2s[i] = s;
    }
    __syncthreads();
    for (int i = tid; i < 1024; i += 256) {
      int r = i >> 5, c = i & 31;
      float s = 0.0f;
      for (int m = 0; m < 32; ++m) s += L2s[r * 32 + m] * Ls[m * 32 + c];
      L3s[i] = s;
    }
    __syncthreads();
    // M stacked [128x32]: rows 0-31 I, 32-63 L, 64-95 2L^2-I, 96-127 4L^3-3L.
    // B-fragments of M^T: MGf[jt][lane][j] = M[col=jt*16+(lane&15)][k=(lane>>4)*8+j]
    u16* MGf = (u16*)(ws + WS_MGF);
    for (int i = tid; i < 4096; i += 256) {
      int jt = i >> 9, lane = (i >> 3) & 63, j = i & 7;
      int col = jt * 16 + (lane & 15);
      int k = ((lane >> 4) << 3) + j;
      int kk = col >> 5, np = col & 31;
      float v;
      if (kk == 0)      v = (np == k) ? 1.0f : 0.0f;
      else if (kk == 1) v = Ls[np * 32 + k];
      else if (kk == 2) v = 2.0f * L2s[np * 32 + k] - (np == k ? 1.0f : 0.0f);
      else              v = 4.0f * L3s[np * 32 + k] - 3.0f * Ls[np * 32 + k];
      MGf[i] = f2bf(v);
    }
    float* B1 = (float*)(ws + WS_B1);
    float* B2 = (float*)(ws + WS_B2);
    if (tid < 128) {
      float s = b1[tid];
      for (int c = 0; c < 60; ++c) s += w1[(c * 5) * 128 + tid];
      B1[tid] = s;
    } else {
      int o = tid - 128;
      float s = b2[o];
      for (int c = 0; c < 128; ++c) s += w2[(c * 5) * 128 + o];
      B2[o] = s;
    }
  } else {
    u16* WT1F = (u16*)(ws + WS_WT1F);
    u16* WT2F = (u16*)(ws + WS_WT2F);
    int g = (blockIdx.x - 1) * 256 + tid;
    // WT1F bits: j[0:3) lane[3:9) ks[9:11) h[11:12) ot[12:15)
    // element = w1 at kterm=ks, c=h*32+q*8+j (0 if c>=60), o=ot*16+(lane&15)
    for (int i = g; i < 32768; i += 16 * 256) {
      int j = i & 7, lane = (i >> 3) & 63, ks = (i >> 9) & 3;
      int h = (i >> 11) & 1, ot = i >> 12;
      int q = lane >> 4;
      int c = h * 32 + q * 8 + j;
      int o = ot * 16 + (lane & 15);
      WT1F[i] = (c < 60) ? f2bf(w1[(c * 5 + ks + 1) * 128 + o]) : (u16)0;
    }
    // WT2F bits: j[0:3) lane[3:9) ks[9:11) h[11:13) mt[13:16)
    // element = w2 at kterm=ks, c2=h*32+q*8+j, o=mt*16+(lane&15)
    for (int i = g; i < 65536; i += 16 * 256) {
      int j = i & 7, lane = (i >> 3) & 63, ks = (i >> 9) & 3;
      int h = (i >> 11) & 3, mt = i >> 13;
      int q = lane >> 4;
      int c2 = h * 32 + q * 8 + j;
      int o = mt * 16 + (lane & 15);
      WT2F[i] = f2bf(w2[(c2 * 5 + ks + 1) * 128 + o]);
    }
  }
}

// 128-thread block, ONE batch per block, 2 waves:
//   G1:     wave w computes kterms {2w, 2w+1}
//   einsum: wave w computes o-tiles {4w..4w+3}
// LDS layouts, ODD dword strides (conflict-free by construction):
//   Xt [64 c][42] u16  (21 dw/row; rows 60..63 zeroed; cols 0..31 used)
//   Ht [128 o][38] u16 (19 dw/row; overlays Xt region)
//   Y  [32 np][138] u16 (69 dw/row; 128 kc-chunk cols; kc = kterm*32 + c_local)
__global__ __launch_bounds__(128, 4) void dgcnn_kernel(
    const float* __restrict__ x,
    const char* __restrict__ ws,
    const float* __restrict__ fc_w,
    const float* __restrict__ fc_b,
    float* __restrict__ out) {
  __shared__ __align__(16) char arena[18560];
  __shared__ float red[4];
  u16* Xt = (u16*)arena;            // 5376 B
  u16* Ht = (u16*)arena;            // 9728 B (after Xt dead)
  u16* Y  = (u16*)(arena + 9728);   // 8832 B

  const u16* MGf  = (const u16*)(ws + WS_MGF);
  const u16* WT1F = (const u16*)(ws + WS_WT1F);
  const u16* WT2F = (const u16*)(ws + WS_WT2F);
  const float* bias1 = (const float*)(ws + WS_B1);
  const float* bias2 = (const float*)(ws + WS_B2);

  const int tid = threadIdx.x;
  const int w = tid >> 6, lane = tid & 63;
  const int l15 = lane & 15, q = lane >> 4;
  const int b = blockIdx.x;
  const f32x4 z4 = {0.0f, 0.0f, 0.0f, 0.0f};

  // M^T B-fragments for this wave's 2 kterms x 2 np-tiles: jt = 4w+t
  bf16x8 mB[4];
#pragma unroll
  for (int t = 0; t < 4; ++t)
    mB[t] = *(const bf16x8*)(MGf + ((4 * w + t) * 64 + lane) * 8);

  // ---- stage x^T; rows 60..63 zeroed ----
  {
    int r = 60 + (tid >> 5), col = tid & 31;
    Xt[r * 42 + col] = 0;
  }
  const float* xb = x + (size_t)b * 1920;
  for (int i = tid; i < 1920; i += 128) {
    int n = i / 60, c = i - n * 60;
    Xt[c * 42 + n] = f2bf(xb[i]);
  }
  __syncthreads();

  // ---------------- layer 1: 2 kc-chunks (c-halves), acc in regs ----------------
  f32x4 acc1[4][2] = {{z4, z4}, {z4, z4}, {z4, z4}, {z4, z4}};  // [ot_][nt]
#pragma unroll
  for (int h = 0; h < 2; ++h) {
    // G1: Y[np][kt*32 + c_local] = T~[kt][np][c = 32h + c_local], kt = 2w+ktl
    {
      bf16x8 aX0 = *(const bf16x8*)&Xt[((2 * h + 0) * 16 + l15) * 42 + q * 8];
      bf16x8 aX1 = *(const bf16x8*)&Xt[((2 * h + 1) * 16 + l15) * 42 + q * 8];
#pragma unroll
      for (int ktl = 0; ktl < 2; ++ktl) {
        f32x4 g00 = MFMA16(aX0, mB[2 * ktl + 0], z4);
        f32x4 g01 = MFMA16(aX0, mB[2 * ktl + 1], z4);
        f32x4 g10 = MFMA16(aX1, mB[2 * ktl + 0], z4);
        f32x4 g11 = MFMA16(aX1, mB[2 * ktl + 1], z4);
        int cb = (2 * w + ktl) * 32 + q * 4;
        uint2 v;
        v.x = pk2bf(g00[0], g00[1]); v.y = pk2bf(g00[2], g00[3]);
        *(uint2*)&Y[l15 * 138 + cb] = v;
        v.x = pk2bf(g01[0], g01[1]); v.y = pk2bf(g01[2], g01[3]);
        *(uint2*)&Y[(16 + l15) * 138 + cb] = v;
        v.x = pk2bf(g10[0], g10[1]); v.y = pk2bf(g10[2], g10[3]);
        *(uint2*)&Y[l15 * 138 + cb + 16] = v;
        v.x = pk2bf(g11[0], g11[1]); v.y = pk2bf(g11[2], g11[3]);
        *(uint2*)&Y[(16 + l15) * 138 + cb + 16] = v;
      }
    }
    __syncthreads();
    // einsum1 partial over this chunk's 128 kc
#pragma unroll
    for (int ks = 0; ks < 4; ++ks) {
      bf16x8 a0 = *(const bf16x8*)&Y[l15 * 138 + ks * 32 + q * 8];
      bf16x8 a1 = *(const bf16x8*)&Y[(16 + l15) * 138 + ks * 32 + q * 8];
#pragma unroll
      for (int ot = 0; ot < 4; ++ot) {
        bf16x8 wf = *(const bf16x8*)(WT1F + ((((4 * w + ot) * 2 + h) * 4 + ks) * 64 + lane) * 8);
        acc1[ot][0] = MFMA16(a0, wf, acc1[ot][0]);
        acc1[ot][1] = MFMA16(a1, wf, acc1[ot][1]);
      }
    }
    if (h == 0) __syncthreads();  // next G1 rewrites Y
  }
  // bias+relu -> Ht (Xt dead: all Xt reads preceded the last post-G1 barrier)
#pragma unroll
  for (int ot = 0; ot < 4; ++ot) {
    int o = (4 * w + ot) * 16 + l15;
    float bv = bias1[o];
#pragma unroll
    for (int nt = 0; nt < 2; ++nt) {
      uint2 v;
      v.x = pk2bf(fmaxf(acc1[ot][nt][0] + bv, 0.0f), fmaxf(acc1[ot][nt][1] + bv, 0.0f));
      v.y = pk2bf(fmaxf(acc1[ot][nt][2] + bv, 0.0f), fmaxf(acc1[ot][nt][3] + bv, 0.0f));
      *(uint2*)&Ht[o * 38 + nt * 16 + q * 4] = v;
    }
  }
  __syncthreads();

  // ---------------- layer 2: 4 kc-chunks (o2-quarters), acc in regs ----------------
  f32x4 acc2[4][2] = {{z4, z4}, {z4, z4}, {z4, z4}, {z4, z4}};  // [ot_][nt]
#pragma unroll
  for (int hh = 0; hh < 4; ++hh) {
    // G1: Y[np][kt*32 + c2_local] = T~2[kt][np][o2 = 32hh + c2_local]
    {
      bf16x8 aH0 = *(const bf16x8*)&Ht[((2 * hh + 0) * 16 + l15) * 38 + q * 8];
      bf16x8 aH1 = *(const bf16x8*)&Ht[((2 * hh + 1) * 16 + l15) * 38 + q * 8];
#pragma unroll
      for (int ktl = 0; ktl < 2; ++ktl) {
        f32x4 g00 = MFMA16(aH0, mB[2 * ktl + 0], z4);
        f32x4 g01 = MFMA16(aH0, mB[2 * ktl + 1], z4);
        f32x4 g10 = MFMA16(aH1, mB[2 * ktl + 0], z4);
        f32x4 g11 = MFMA16(aH1, mB[2 * ktl + 1], z4);
        int cb = (2 * w + ktl) * 32 + q * 4;
        uint2 v;
        v.x = pk2bf(g00[0], g00[1]); v.y = pk2bf(g00[2], g00[3]);
        *(uint2*)&Y[l15 * 138 + cb] = v;
        v.x = pk2bf(g01[0], g01[1]); v.y = pk2bf(g01[2], g01[3]);
        *(uint2*)&Y[(16 + l15) * 138 + cb] = v;
        v.x = pk2bf(g10[0], g10[1]); v.y = pk2bf(g10[2], g10[3]);
        *(uint2*)&Y[l15 * 138 + cb + 16] = v;
        v.x = pk2bf(g11[0], g11[1]); v.y = pk2bf(g11[2], g11[3]);
        *(uint2*)&Y[(16 + l15) * 138 + cb + 16] = v;
      }
    }
    __syncthreads();
    // einsum2 partial (flipped): D[o][n] += Wp2^T[o][chunk kc] @ Y^T[kc][n]
#pragma unroll
    for (int ks = 0; ks < 4; ++ks) {
      bf16x8 by0 = *(const bf16x8*)&Y[l15 * 138 + ks * 32 + q * 8];
      bf16x8 by1 = *(const bf16x8*)&Y[(16 + l15) * 138 + ks * 32 + q * 8];
#pragma unroll
      for (int ot = 0; ot < 4; ++ot) {
        bf16x8 aw = *(const bf16x8*)(WT2F + ((((4 * w + ot) * 4 + hh) * 4 + ks) * 64 + lane) * 8);
        acc2[ot][0] = MFMA16(aw, by0, acc2[ot][0]);
        acc2[ot][1] = MFMA16(aw, by1, acc2[ot][1]);
      }
    }
    if (hh < 3) __syncthreads();  // next G1 rewrites Y
  }

  // ---- epilogue: bias2+relu in regs, fc directly from accumulators ----
  float p0 = 0.0f, p1 = 0.0f;
#pragma unroll
  for (int ot = 0; ot < 4; ++ot) {
    int ob = (4 * w + ot) * 16 + q * 4;  // o base, 4 contiguous per lane
    float4 bv = *(const float4*)&bias2[ob];
#pragma unroll
    for (int nt = 0; nt < 2; ++nt) {
      int n = nt * 16 + l15;
      float4 w0 = *(const float4*)&fc_w[n * 128 + ob];
      float4 w1v = *(const float4*)&fc_w[4096 + n * 128 + ob];
      float h0 = fmaxf(acc2[ot][nt][0] + bv.x, 0.0f);
      float h1 = fmaxf(acc2[ot][nt][1] + bv.y, 0.0f);
      float h2 = fmaxf(acc2[ot][nt][2] + bv.z, 0.0f);
      float h3 = fmaxf(acc2[ot][nt][3] + bv.w, 0.0f);
      p0 = fmaf(h0, w0.x, fmaf(h1, w0.y, fmaf(h2, w0.z, fmaf(h3, w0.w, p0))));
      p1 = fmaf(h0, w1v.x, fmaf(h1, w1v.y, fmaf(h2, w1v.z, fmaf(h3, w1v.w, p1))));
    }
  }
#pragma unroll
  for (int off = 32; off >= 1; off >>= 1) {
    p0 += __shfl_xor(p0, off);
    p1 += __shfl_xor(p1, off);
  }
  if (lane == 0) {
    red[w * 2 + 0] = p0;
    red[w * 2 + 1] = p1;
  }
  __syncthreads();
  if (tid < 2) {
    out[b * 2 + tid] = red[tid] + red[2 + tid] + fc_b[tid];
  }
}

extern "C" void kernel_launch(void* const* d_in, const int* in_sizes, int n_in,
                              void* d_out, int out_size, void* d_ws, size_t ws_size,
                              hipStream_t stream) {
  const float* x        = (const float*)d_in[0];
  const float* adj      = (const float*)d_in[1];
  const float* adj_bias = (const float*)d_in[2];
  const float* w1       = (const float*)d_in[3];
  const float* b1       = (const float*)d_in[4];
  const float* w2       = (const float*)d_in[5];
  const float* b2       = (const float*)d_in[6];
  const float* fc_w     = (const float*)d_in[7];
  const float* fc_b     = (const float*)d_in[8];
  float* out = (float*)d_out;
  char* ws   = (char*)d_ws;

  prep_kernel<<<17, 256, 0, stream>>>(adj, adj_bias, w1, b1, w2, b2, ws);
  dgcnn_kernel<<<8192, 128, 0, stream>>>(x, ws, fc_w, fc_b, out);
}